// Round 1
// baseline (194.910 us; speedup 1.0000x reference)
//
#include <hip/hip_runtime.h>
#include <hip/hip_bf16.h>
#include <stdint.h>

typedef __attribute__((ext_vector_type(4))) float f32x4;
typedef __attribute__((ext_vector_type(8))) short s16x8;
typedef __attribute__((ext_vector_type(4))) unsigned int u32x4;

// ---------------- ws layout ----------------
// spk   : uint32 [40][1024][16]  (bit f%32 of word f/32 at step t, row b) = 2,621,440 B
// whi   : bf16 [128][512]  hi part of w_in                               =   131,072 B
// wlo   : bf16 [128][512]  lo part                                       =   131,072 B
// I     : f32 [40][1024][128] input currents                             = 20,971,520 B
#define OFF_WHI 2621440
#define OFF_WLO 2752512
#define OFF_I   2883584

__device__ __forceinline__ void gload16(const void* g, void* l) {
    __builtin_amdgcn_global_load_lds(
        (const __attribute__((address_space(1))) uint32_t*)g,
        (__attribute__((address_space(3))) uint32_t*)l, 16, 0, 0);
}

// K0: split w_in into bf16 hi/lo (layout kept [h][k] row-major = B^T, contiguous K)
__global__ __launch_bounds__(256) void k_prep(const float* __restrict__ w_in,
                                              __hip_bfloat16* __restrict__ whi,
                                              __hip_bfloat16* __restrict__ wlo) {
    int i = blockIdx.x * 256 + threadIdx.x;   // 65536 total
    float w = w_in[i];
    __hip_bfloat16 h = __float2bfloat16(w);
    whi[i] = h;
    wlo[i] = __float2bfloat16(w - __bfloat162float(h));
}

// K1: constant-current LIF encoder, spikes ballot-packed to bits
__global__ __launch_bounds__(256) void k_encode(const float* __restrict__ x,
                                                uint32_t* __restrict__ spk) {
    int gid  = blockIdx.x * 256 + threadIdx.x;   // 1024*512
    int b    = gid >> 9;
    int f    = gid & 511;
    int lane = threadIdx.x & 63;
    float xv  = x[b * 256 + (f & 255)];
    float cur = (f < 256) ? fmaxf(50.f * xv, 0.f) : fmaxf(-50.f * xv, 0.f);
    int wbase = (f >> 6) << 1;                  // first of 2 words this wave covers
    float v = 0.f;
    for (int t = 0; t < 40; ++t) {
        v = v + 0.1f * (cur - v);               // v + dt*tau_mem_inv*(-v + i)
        bool z = (v - 1.0f) > 0.f;
        unsigned long long m = __ballot(z);
        if (z) v = 0.f;
        if (lane == 0)
            *(unsigned long long*)&spk[(size_t)(t * 1024 + b) * 16 + wbase] = m;
    }
}

// K2: I[m][h] = spikes[m][:] @ w_in.T  via MFMA, w_in as bf16 hi+lo (exact 0/1 A)
__global__ __launch_bounds__(256) void k_ingemm(const uint32_t* __restrict__ spk,
                                                const __hip_bfloat16* __restrict__ whi,
                                                const __hip_bfloat16* __restrict__ wlo,
                                                float* __restrict__ I) {
    __shared__ uint32_t lut[256][4];
    __shared__ __hip_bfloat16 Bh[128 * 32];
    __shared__ __hip_bfloat16 Bl[128 * 32];

    const int tid = threadIdx.x;
    {   // byte -> 8 packed bf16 (0/1) LUT
        uint32_t by = tid, r0 = 0, r1 = 0, r2 = 0, r3 = 0;
        if (by & 1)   r0 |= 0x3F80u;
        if (by & 2)   r0 |= 0x3F800000u;
        if (by & 4)   r1 |= 0x3F80u;
        if (by & 8)   r1 |= 0x3F800000u;
        if (by & 16)  r2 |= 0x3F80u;
        if (by & 32)  r2 |= 0x3F800000u;
        if (by & 64)  r3 |= 0x3F80u;
        if (by & 128) r3 |= 0x3F800000u;
        lut[tid][0] = r0; lut[tid][1] = r1; lut[tid][2] = r2; lut[tid][3] = r3;
    }

    const int lane = tid & 63, wid = tid >> 6;
    const int wm = wid >> 1, wn = wid & 1;      // 2x2 wave grid, 64x64 per wave
    const int fr = lane & 15, fo = lane >> 4;
    const int m0 = blockIdx.x * 128;

    f32x4 acc[4][4];
#pragma unroll
    for (int a = 0; a < 4; ++a)
#pragma unroll
        for (int b = 0; b < 4; ++b) acc[a][b] = (f32x4)0.f;

    int arow[4];
#pragma unroll
    for (int mi = 0; mi < 4; ++mi) arow[mi] = (m0 + wm * 64 + mi * 16 + fr) * 16;

    for (int ks = 0; ks < 16; ++ks) {
        // stage B hi/lo 32-K slice: 512 16B-chunks each, 2 per thread
#pragma unroll
        for (int cc = 0; cc < 2; ++cc) {
            int c = tid + cc * 256;
            int n = c >> 2, sub = c & 3;
            int goff = n * 512 + ks * 32 + sub * 8;
            gload16(whi + goff, (__hip_bfloat16*)Bh + c * 8);
            gload16(wlo + goff, (__hip_bfloat16*)Bl + c * 8);
        }
        uint32_t wrd[4];
#pragma unroll
        for (int mi = 0; mi < 4; ++mi) wrd[mi] = spk[arow[mi] + ks];
        asm volatile("s_waitcnt vmcnt(0)" ::: "memory");
        __syncthreads();

        s16x8 af[4], bhf[4], blf[4];
#pragma unroll
        for (int mi = 0; mi < 4; ++mi) {
            uint32_t by = (wrd[mi] >> (fo * 8)) & 0xFFu;
            union { u32x4 u; s16x8 v; } cv;
            cv.u = *(const u32x4*)lut[by];
            af[mi] = cv.v;
        }
#pragma unroll
        for (int ni = 0; ni < 4; ++ni) {
            int ncol = wn * 64 + ni * 16 + fr;
            bhf[ni] = *(const s16x8*)&Bh[ncol * 32 + fo * 8];
            blf[ni] = *(const s16x8*)&Bl[ncol * 32 + fo * 8];
        }
#pragma unroll
        for (int mi = 0; mi < 4; ++mi)
#pragma unroll
            for (int ni = 0; ni < 4; ++ni) {
                acc[mi][ni] = __builtin_amdgcn_mfma_f32_16x16x32_bf16(af[mi], bhf[ni], acc[mi][ni], 0, 0, 0);
                acc[mi][ni] = __builtin_amdgcn_mfma_f32_16x16x32_bf16(af[mi], blf[ni], acc[mi][ni], 0, 0, 0);
            }
        __syncthreads();
    }
#pragma unroll
    for (int mi = 0; mi < 4; ++mi) {
        int r0 = m0 + wm * 64 + mi * 16 + fo * 4;   // C/D: row=(lane>>4)*4+reg
#pragma unroll
        for (int ni = 0; ni < 4; ++ni) {
            int col = wn * 64 + ni * 16 + fr;       // C/D: col=lane&15
#pragma unroll
            for (int r = 0; r < 4; ++r)
                I[(size_t)(r0 + r) * 128 + col] = acc[mi][ni][r];
        }
    }
}

// K3: recurrent LIF + LI readouts + max + softmax. 2 batch rows per WG.
__global__ __launch_bounds__(256) void k_recur(const float* __restrict__ I,
                                               const float* __restrict__ w_rec,
                                               const float* __restrict__ w_actor,
                                               const float* __restrict__ w_critic,
                                               float* __restrict__ out) {
    __shared__ float zL[2][128];
    __shared__ float wa[19][132];     // rows 0..17 actor, 18 critic; padded stride
    __shared__ float red[2][20];

    const int tid = threadIdx.x;
    const int h = tid & 127, bl = tid >> 7;
    const int b = blockIdx.x * 2 + bl;

    // w_rec row resident in registers
    float wreg[128];
#pragma unroll
    for (int j = 0; j < 32; ++j) {
        float4 w4 = *(const float4*)&w_rec[h * 128 + j * 4];
        wreg[j * 4 + 0] = w4.x; wreg[j * 4 + 1] = w4.y;
        wreg[j * 4 + 2] = w4.z; wreg[j * 4 + 3] = w4.w;
    }
    for (int idx = tid; idx < 18 * 128; idx += 256)
        wa[idx >> 7][idx & 127] = w_actor[idx];
    if (tid < 128) wa[18][tid] = w_critic[tid];
    zL[bl][h] = 0.f;
    __syncthreads();

    const int ra = h >> 2, rq = h & 3;          // 4 lanes per readout channel
    const bool ract = ra < 19;
    float v = 0.f, ci = 0.f;
    float va = 0.f, ia = 0.f, ma = -1e30f;      // valid on rq==0 && ract

    for (int t = 0; t < 40; ++t) {
        // recurrent drive from z_{t-1}
        float rec = 0.f;
#pragma unroll
        for (int j = 0; j < 32; ++j) {
            float4 z4 = *(const float4*)&zL[bl][j * 4];   // wave-broadcast
            rec = fmaf(z4.x, wreg[j * 4 + 0], rec);
            rec = fmaf(z4.y, wreg[j * 4 + 1], rec);
            rec = fmaf(z4.z, wreg[j * 4 + 2], rec);
            rec = fmaf(z4.w, wreg[j * 4 + 3], rec);
        }
        float It = I[(size_t)(t * 1024 + b) * 128 + h];
        float v_dec = v + 0.1f * (ci - v);
        float i_dec = ci - 0.2f * ci;
        float z = ((v_dec - 1.0f) > 0.f) ? 1.f : 0.f;
        v = (z > 0.f) ? 0.f : v_dec;
        ci = i_dec + It + rec;
        __syncthreads();
        zL[bl][h] = z;
        __syncthreads();
        // readouts use z_t
        float part = 0.f;
        if (ract) {
#pragma unroll
            for (int j = 0; j < 8; ++j) {
                float4 z4 = *(const float4*)&zL[bl][rq * 32 + j * 4];
                float4 w4 = *(const float4*)&wa[ra][rq * 32 + j * 4];
                part = fmaf(z4.x, w4.x, part);
                part = fmaf(z4.y, w4.y, part);
                part = fmaf(z4.z, w4.z, part);
                part = fmaf(z4.w, w4.w, part);
            }
        }
        part += __shfl_xor(part, 1);
        part += __shfl_xor(part, 2);
        if (ract && rq == 0) {
            va = va + 0.1f * (ia - va);         // uses old ia
            ia = ia - 0.2f * ia + part;
            ma = fmaxf(ma, va);
        }
    }
    if (ract && rq == 0) red[bl][ra] = ma;
    __syncthreads();
    float mx = -1e30f;
#pragma unroll
    for (int a2 = 0; a2 < 18; ++a2) mx = fmaxf(mx, red[bl][a2]);
    float s = 0.f;
#pragma unroll
    for (int a2 = 0; a2 < 18; ++a2) s += expf(red[bl][a2] - mx);
    if (h < 18) out[b * 18 + h] = expf(red[bl][h] - mx) / s;
    if (h == 18) out[18432 + b] = red[bl][18];
}

extern "C" void kernel_launch(void* const* d_in, const int* in_sizes, int n_in,
                              void* d_out, int out_size, void* d_ws, size_t ws_size,
                              hipStream_t stream) {
    const float* x        = (const float*)d_in[0];
    const float* w_in     = (const float*)d_in[1];
    const float* w_rec    = (const float*)d_in[2];
    const float* w_actor  = (const float*)d_in[3];
    const float* w_critic = (const float*)d_in[4];
    float* out = (float*)d_out;
    char* ws = (char*)d_ws;
    uint32_t*        spk = (uint32_t*)ws;
    __hip_bfloat16*  whi = (__hip_bfloat16*)(ws + OFF_WHI);
    __hip_bfloat16*  wlo = (__hip_bfloat16*)(ws + OFF_WLO);
    float*           I   = (float*)(ws + OFF_I);

    hipLaunchKernelGGL(k_prep,   dim3(256),  dim3(256), 0, stream, w_in, whi, wlo);
    hipLaunchKernelGGL(k_encode, dim3(2048), dim3(256), 0, stream, x, spk);
    hipLaunchKernelGGL(k_ingemm, dim3(320),  dim3(256), 0, stream, spk, whi, wlo, I);
    hipLaunchKernelGGL(k_recur,  dim3(512),  dim3(256), 0, stream, I, w_rec, w_actor, w_critic, out);
}

// Round 5
// 174.773 us; speedup vs baseline: 1.1152x; 1.1152x over previous
//
#include <hip/hip_runtime.h>
#include <hip/hip_bf16.h>
#include <stdint.h>

typedef __attribute__((ext_vector_type(4))) float f32x4;
typedef __attribute__((ext_vector_type(8))) short s16x8;
typedef __attribute__((ext_vector_type(4))) unsigned int u32x4;

// ---------------- ws layout (bytes) ----------------
// spk   : u32 [40][1024][16] encoder spike bits   @ 0        (2,621,440)
// whi   : bf16 [128][512]  w_in hi                @ 2621440  (131,072)
// wlo   : bf16 [128][512]  w_in lo                @ 2752512  (131,072)
// (gap: former lo2 slot, unused)                  @ 2883584  (131,072)
// wahi  : bf16 [32][128]   actor+critic hi        @ 3014656  (8,192)
// walo  : bf16 [32][128]   actor+critic lo        @ 3022848  (8,192)
// I     : f32 [40][1024][128]                     @ 3031040  (20,971,520)
// zbits : u64 [40][1024][2]                       @ 24002560 (655,360)
// part  : f32 [40960][20]                         @ 24657920 (3,276,800)
#define OFF_WHI  2621440
#define OFF_WLO  2752512
#define OFF_WAHI 3014656
#define OFF_WALO 3022848
#define OFF_I    3031040
#define OFF_ZB   24002560
#define OFF_PART 24657920

__device__ __forceinline__ void lut_init(uint32_t lut[256][4], int tid) {
    if (tid < 256) {
        uint32_t by = tid, r0 = 0, r1 = 0, r2 = 0, r3 = 0;
        if (by & 1)   r0 |= 0x3F80u;
        if (by & 2)   r0 |= 0x3F800000u;
        if (by & 4)   r1 |= 0x3F80u;
        if (by & 8)   r1 |= 0x3F800000u;
        if (by & 16)  r2 |= 0x3F80u;
        if (by & 32)  r2 |= 0x3F800000u;
        if (by & 64)  r3 |= 0x3F80u;
        if (by & 128) r3 |= 0x3F800000u;
        lut[tid][0] = r0; lut[tid][1] = r1; lut[tid][2] = r2; lut[tid][3] = r3;
    }
}

// K0: 2-way bf16 hi/lo split (bitwise-R1), plus actor/critic hi/lo for readout
__global__ __launch_bounds__(256) void k_prep(const float* __restrict__ w_in,
                                              const float* __restrict__ w_actor,
                                              const float* __restrict__ w_critic,
                                              __hip_bfloat16* __restrict__ whi,
                                              __hip_bfloat16* __restrict__ wlo,
                                              __hip_bfloat16* __restrict__ wahi,
                                              __hip_bfloat16* __restrict__ walo) {
    int i = blockIdx.x * 256 + threadIdx.x;   // 65536
    float w = w_in[i];
    __hip_bfloat16 h = __float2bfloat16(w);
    whi[i] = h;
    wlo[i] = __float2bfloat16(w - __bfloat162float(h));
    if (i < 4096) {
        int a = i >> 7, j = i & 127;
        float v = (a < 18) ? w_actor[a * 128 + j] : ((a == 18) ? w_critic[j] : 0.f);
        __hip_bfloat16 vh = __float2bfloat16(v);
        wahi[i] = vh;
        walo[i] = __float2bfloat16(v - __bfloat162float(vh));
    }
}

// K1: constant-current LIF encoder — verbatim R1 arithmetic
__global__ __launch_bounds__(256) void k_encode(const float* __restrict__ x,
                                                uint32_t* __restrict__ spk) {
    int gid  = blockIdx.x * 256 + threadIdx.x;   // 1024*512
    int b    = gid >> 9;
    int f    = gid & 511;
    int lane = threadIdx.x & 63;
    float xv  = x[b * 256 + (f & 255)];
    float cur = (f < 256) ? fmaxf(50.f * xv, 0.f) : fmaxf(-50.f * xv, 0.f);
    int wbase = (f >> 6) << 1;
    float v = 0.f;
    for (int t = 0; t < 40; ++t) {
        v = v + 0.1f * (cur - v);
        bool z = (v - 1.0f) > 0.f;
        unsigned long long m = __ballot(z);
        if (z) v = 0.f;
        if (lane == 0)
            *(unsigned long long*)&spk[(size_t)(t * 1024 + b) * 16 + wbase] = m;
    }
}

// K2: I = spikes @ w_in.T via MFMA, hi/lo chain in R1's exact order (hi,lo per ks,
// ks ascending, single acc). 256 WGs x 512 thr; 8 waves each own 16 cols.
__global__ __launch_bounds__(512, 1) void k_ingemm(const uint32_t* __restrict__ spk,
                                                   const __hip_bfloat16* __restrict__ whi,
                                                   const __hip_bfloat16* __restrict__ wlo,
                                                   float* __restrict__ I) {
    __shared__ uint32_t lut[256][4];
    const int tid = threadIdx.x;
    lut_init(lut, tid);
    const int lane = tid & 63, wid = tid >> 6;   // 8 waves
    const int fr = lane & 15, fo = lane >> 4;
    const int n0 = wid * 16;

    // B frags: col = n0+fr, k = ks*32 + fo*8
    s16x8 bh[16], bl[16];
#pragma unroll
    for (int ks = 0; ks < 16; ++ks) {
        int off = (n0 + fr) * 512 + ks * 32 + fo * 8;
        bh[ks] = *(const s16x8*)(whi + off);
        bl[ks] = *(const s16x8*)(wlo + off);
    }
    __syncthreads();

    const int m0 = blockIdx.x * 160;
    for (int mt = 0; mt < 10; ++mt) {
        int mrow = m0 + mt * 16 + fr;
        u32x4 w0 = *(const u32x4*)&spk[mrow * 16];
        u32x4 w1 = *(const u32x4*)&spk[mrow * 16 + 4];
        u32x4 w2 = *(const u32x4*)&spk[mrow * 16 + 8];
        u32x4 w3 = *(const u32x4*)&spk[mrow * 16 + 12];
        f32x4 acc = (f32x4)0.f;
#pragma unroll
        for (int ks = 0; ks < 16; ++ks) {
            uint32_t word = (ks < 4) ? w0[ks & 3] : (ks < 8) ? w1[ks & 3]
                          : (ks < 12) ? w2[ks & 3] : w3[ks & 3];
            uint32_t by = (word >> (fo * 8)) & 0xFFu;
            union { u32x4 u; s16x8 v; } cv;
            cv.u = *(const u32x4*)lut[by];
            s16x8 af = cv.v;
            acc = __builtin_amdgcn_mfma_f32_16x16x32_bf16(af, bh[ks], acc, 0, 0, 0);
            acc = __builtin_amdgcn_mfma_f32_16x16x32_bf16(af, bl[ks], acc, 0, 0, 0);
        }
        int row0 = m0 + mt * 16 + fo * 4;
        int col = n0 + fr;
#pragma unroll
        for (int r = 0; r < 4; ++r)
            I[(size_t)(row0 + r) * 128 + col] = acc[r];
    }
}

// K3: recurrent LIF. 1 wave/batch row; w_rec in 256 VGPRs; z via ballot.
// FIX: recurrent drive uses PREVIOUS step's z (m0p/m1p), as in the reference.
// rec arithmetic = bitwise R1: single-acc ascending fmaf chain with zf in {0,1}.
__global__ __launch_bounds__(64, 1) void k_recur(const float* __restrict__ I,
                                                 const float* __restrict__ w_rec,
                                                 unsigned long long* __restrict__ zbits) {
    const int l = threadIdx.x;
    const int b = blockIdx.x;

    float wa_r[128], wb_r[128];
#pragma unroll
    for (int j = 0; j < 32; ++j) {
        float4 w4 = *(const float4*)&w_rec[l * 128 + j * 4];
        wa_r[j * 4 + 0] = w4.x; wa_r[j * 4 + 1] = w4.y;
        wa_r[j * 4 + 2] = w4.z; wa_r[j * 4 + 3] = w4.w;
        float4 v4 = *(const float4*)&w_rec[(l + 64) * 128 + j * 4];
        wb_r[j * 4 + 0] = v4.x; wb_r[j * 4 + 1] = v4.y;
        wb_r[j * 4 + 2] = v4.z; wb_r[j * 4 + 3] = v4.w;
    }

    float v_a = 0.f, i_a = 0.f, v_b = 0.f, i_b = 0.f;
    float Ia = I[(size_t)b * 128 + l];
    float Ib = I[(size_t)b * 128 + l + 64];
    unsigned long long m0p = 0ull, m1p = 0ull;   // z_{t-1} masks (z init = 0)
    unsigned long long* zout = zbits + (size_t)b * 2;

    for (int t = 0; t < 40; ++t) {
        int tn = (t < 39) ? t + 1 : 39;
        float nIa = I[(size_t)(tn * 1024 + b) * 128 + l];
        float nIb = I[(size_t)(tn * 1024 + b) * 128 + l + 64];

        // recurrent drive from z_{t-1}: single-acc ascending fmaf chain (R1 order)
        float rec_a = 0.f, rec_b = 0.f;
#pragma unroll
        for (int j = 0; j < 64; ++j) {
            float zf = ((m0p >> j) & 1ull) ? 1.0f : 0.0f;
            rec_a = fmaf(zf, wa_r[j], rec_a);
            rec_b = fmaf(zf, wb_r[j], rec_b);
        }
#pragma unroll
        for (int j = 0; j < 64; ++j) {
            float zf = ((m1p >> j) & 1ull) ? 1.0f : 0.0f;
            rec_a = fmaf(zf, wa_r[64 + j], rec_a);
            rec_b = fmaf(zf, wb_r[64 + j], rec_b);
        }

        // LIF update — verbatim R1 expressions
        float vda = v_a + 0.1f * (i_a - v_a);
        float vdb = v_b + 0.1f * (i_b - v_b);
        float ida = i_a - 0.2f * i_a;
        float idb = i_b - 0.2f * i_b;
        bool za = (vda - 1.0f) > 0.f;
        bool zb = (vdb - 1.0f) > 0.f;
        unsigned long long m0 = __ballot(za);
        unsigned long long m1 = __ballot(zb);
        v_a = za ? 0.f : vda;
        v_b = zb ? 0.f : vdb;
        if (l == 0) {
            zout[(size_t)t * 2048]     = m0;
            zout[(size_t)t * 2048 + 1] = m1;
        }
        i_a = ida + Ia + rec_a;    // (i_dec + I_t) + rec, R1 association
        i_b = idb + Ib + rec_b;
        Ia = nIa; Ib = nIb;
        m0p = m0; m1p = m1;
    }
}

// K4: part[m][a] = z[m][:] @ [w_actor;w_critic].T via MFMA (hi/lo; smooth path)
__global__ __launch_bounds__(256) void k_parts(const uint32_t* __restrict__ zb,
                                               const __hip_bfloat16* __restrict__ wahi,
                                               const __hip_bfloat16* __restrict__ walo,
                                               float* __restrict__ part) {
    __shared__ uint32_t lut[256][4];
    const int tid = threadIdx.x;
    lut_init(lut, tid);
    const int lane = tid & 63, wid = tid >> 6;
    const int fr = lane & 15, fo = lane >> 4;

    s16x8 bf[2][4][2];
#pragma unroll
    for (int ni = 0; ni < 2; ++ni)
#pragma unroll
        for (int ks = 0; ks < 4; ++ks) {
            int off = (ni * 16 + fr) * 128 + ks * 32 + fo * 8;
            bf[ni][ks][0] = *(const s16x8*)(wahi + off);
            bf[ni][ks][1] = *(const s16x8*)(walo + off);
        }
    __syncthreads();

    const int m0 = blockIdx.x * 128 + wid * 32;
#pragma unroll
    for (int mt = 0; mt < 2; ++mt) {
        int mrow = m0 + mt * 16 + fr;
        u32x4 w = *(const u32x4*)&zb[(size_t)mrow * 4];
        f32x4 acc[2];
        acc[0] = (f32x4)0.f; acc[1] = (f32x4)0.f;
#pragma unroll
        for (int ks = 0; ks < 4; ++ks) {
            uint32_t by = (w[ks] >> (fo * 8)) & 0xFFu;
            union { u32x4 u; s16x8 v; } cv;
            cv.u = *(const u32x4*)lut[by];
            s16x8 af = cv.v;
            acc[0] = __builtin_amdgcn_mfma_f32_16x16x32_bf16(af, bf[0][ks][0], acc[0], 0, 0, 0);
            acc[0] = __builtin_amdgcn_mfma_f32_16x16x32_bf16(af, bf[0][ks][1], acc[0], 0, 0, 0);
            acc[1] = __builtin_amdgcn_mfma_f32_16x16x32_bf16(af, bf[1][ks][0], acc[1], 0, 0, 0);
            acc[1] = __builtin_amdgcn_mfma_f32_16x16x32_bf16(af, bf[1][ks][1], acc[1], 0, 0, 0);
        }
        int row0 = m0 + mt * 16 + fo * 4;
#pragma unroll
        for (int r = 0; r < 4; ++r) {
            part[(size_t)(row0 + r) * 20 + fr] = acc[0][r];
            if (fr < 4) part[(size_t)(row0 + r) * 20 + 16 + fr] = acc[1][r];
        }
    }
}

// K5: LI scan + max + softmax (R1 expressions; smooth path)
__global__ __launch_bounds__(256) void k_scan(const float* __restrict__ part,
                                              float* __restrict__ out) {
    int gid = blockIdx.x * 256 + threadIdx.x;   // 1024*32
    int b = gid >> 5, a = gid & 31;
    float va = 0.f, ia = 0.f, ma = -1e30f;
    for (int t = 0; t < 40; ++t) {
        float p = (a < 20) ? part[(size_t)(t * 1024 + b) * 20 + a] : 0.f;
        va = va + 0.1f * (ia - va);
        ia = ia - 0.2f * ia + p;
        ma = fmaxf(ma, va);
    }
    float mx = (a < 18) ? ma : -1e30f;
#pragma unroll
    for (int d = 1; d < 32; d <<= 1) mx = fmaxf(mx, __shfl_xor(mx, d, 32));
    float e = (a < 18) ? expf(ma - mx) : 0.f;
    float s = e;
#pragma unroll
    for (int d = 1; d < 32; d <<= 1) s += __shfl_xor(s, d, 32);
    if (a < 18) out[b * 18 + a] = e / s;
    if (a == 18) out[18432 + b] = ma;
}

extern "C" void kernel_launch(void* const* d_in, const int* in_sizes, int n_in,
                              void* d_out, int out_size, void* d_ws, size_t ws_size,
                              hipStream_t stream) {
    const float* x        = (const float*)d_in[0];
    const float* w_in     = (const float*)d_in[1];
    const float* w_rec    = (const float*)d_in[2];
    const float* w_actor  = (const float*)d_in[3];
    const float* w_critic = (const float*)d_in[4];
    float* out = (float*)d_out;
    char* ws = (char*)d_ws;
    uint32_t*           spk  = (uint32_t*)ws;
    __hip_bfloat16*     whi  = (__hip_bfloat16*)(ws + OFF_WHI);
    __hip_bfloat16*     wlo  = (__hip_bfloat16*)(ws + OFF_WLO);
    __hip_bfloat16*     wahi = (__hip_bfloat16*)(ws + OFF_WAHI);
    __hip_bfloat16*     walo = (__hip_bfloat16*)(ws + OFF_WALO);
    float*              I    = (float*)(ws + OFF_I);
    unsigned long long* zb   = (unsigned long long*)(ws + OFF_ZB);
    float*              part = (float*)(ws + OFF_PART);

    hipLaunchKernelGGL(k_prep,   dim3(256),  dim3(256), 0, stream, w_in, w_actor, w_critic, whi, wlo, wahi, walo);
    hipLaunchKernelGGL(k_encode, dim3(2048), dim3(256), 0, stream, x, spk);
    hipLaunchKernelGGL(k_ingemm, dim3(256),  dim3(512), 0, stream, spk, whi, wlo, I);
    hipLaunchKernelGGL(k_recur,  dim3(1024), dim3(64),  0, stream, I, w_rec, zb);
    hipLaunchKernelGGL(k_parts,  dim3(320),  dim3(256), 0, stream, (const uint32_t*)zb, wahi, walo, part);
    hipLaunchKernelGGL(k_scan,   dim3(128),  dim3(256), 0, stream, part, out);
}

// Round 6
// 173.647 us; speedup vs baseline: 1.1224x; 1.0065x over previous
//
#include <hip/hip_runtime.h>
#include <hip/hip_bf16.h>
#include <stdint.h>

typedef __attribute__((ext_vector_type(4))) float f32x4;
typedef __attribute__((ext_vector_type(8))) short s16x8;
typedef __attribute__((ext_vector_type(4))) unsigned int u32x4;

// ---------------- ws layout (bytes) ----------------
// spk   : u32 [40][1024][16] encoder spike bits   @ 0        (2,621,440)
// whi   : bf16 [128][512]  w_in hi                @ 2621440  (131,072)
// wlo   : bf16 [128][512]  w_in lo                @ 2752512  (131,072)
// wahi  : bf16 [32][128]   actor+critic hi        @ 3014656  (8,192)
// walo  : bf16 [32][128]   actor+critic lo        @ 3022848  (8,192)
// I     : f32 [40][1024][128]                     @ 3031040  (20,971,520)
// zbits : u64 [40][1024][2]                       @ 24002560 (655,360)
#define OFF_WHI  2621440
#define OFF_WLO  2752512
#define OFF_WAHI 3014656
#define OFF_WALO 3022848
#define OFF_I    3031040
#define OFF_ZB   24002560

__device__ __forceinline__ void lut_entry(uint32_t by, uint32_t* r) {
    uint32_t r0 = 0, r1 = 0, r2 = 0, r3 = 0;
    if (by & 1)   r0 |= 0x3F80u;
    if (by & 2)   r0 |= 0x3F800000u;
    if (by & 4)   r1 |= 0x3F80u;
    if (by & 8)   r1 |= 0x3F800000u;
    if (by & 16)  r2 |= 0x3F80u;
    if (by & 32)  r2 |= 0x3F800000u;
    if (by & 64)  r3 |= 0x3F80u;
    if (by & 128) r3 |= 0x3F800000u;
    r[0] = r0; r[1] = r1; r[2] = r2; r[3] = r3;
}

// K_A: fused weight-split (blocks >= 2048) + LIF encoder (blocks < 2048)
__global__ __launch_bounds__(256) void k_prep_enc(const float* __restrict__ x,
                                                  const float* __restrict__ w_in,
                                                  const float* __restrict__ w_actor,
                                                  const float* __restrict__ w_critic,
                                                  uint32_t* __restrict__ spk,
                                                  __hip_bfloat16* __restrict__ whi,
                                                  __hip_bfloat16* __restrict__ wlo,
                                                  __hip_bfloat16* __restrict__ wahi,
                                                  __hip_bfloat16* __restrict__ walo) {
    const int bid = blockIdx.x;
    if (bid < 2048) {
        // ---- encoder: verbatim R1/R5 arithmetic ----
        int gid  = bid * 256 + threadIdx.x;   // 1024*512
        int b    = gid >> 9;
        int f    = gid & 511;
        int lane = threadIdx.x & 63;
        float xv  = x[b * 256 + (f & 255)];
        float cur = (f < 256) ? fmaxf(50.f * xv, 0.f) : fmaxf(-50.f * xv, 0.f);
        int wbase = (f >> 6) << 1;
        float v = 0.f;
        for (int t = 0; t < 40; ++t) {
            v = v + 0.1f * (cur - v);
            bool z = (v - 1.0f) > 0.f;
            unsigned long long m = __ballot(z);
            if (z) v = 0.f;
            if (lane == 0)
                *(unsigned long long*)&spk[(size_t)(t * 1024 + b) * 16 + wbase] = m;
        }
    } else {
        // ---- hi/lo weight split (bitwise-R1) ----
        int i = (bid - 2048) * 256 + threadIdx.x;   // 65536
        float w = w_in[i];
        __hip_bfloat16 h = __float2bfloat16(w);
        whi[i] = h;
        wlo[i] = __float2bfloat16(w - __bfloat162float(h));
        if (i < 4096) {
            int a = i >> 7, j = i & 127;
            float v = (a < 18) ? w_actor[a * 128 + j] : ((a == 18) ? w_critic[j] : 0.f);
            __hip_bfloat16 vh = __float2bfloat16(v);
            wahi[i] = vh;
            walo[i] = __float2bfloat16(v - __bfloat162float(vh));
        }
    }
}

// K_B: I = spikes @ w_in.T via MFMA (unchanged from R5)
__global__ __launch_bounds__(512, 1) void k_ingemm(const uint32_t* __restrict__ spk,
                                                   const __hip_bfloat16* __restrict__ whi,
                                                   const __hip_bfloat16* __restrict__ wlo,
                                                   float* __restrict__ I) {
    __shared__ uint32_t lut[256][4];
    const int tid = threadIdx.x;
    if (tid < 256) lut_entry(tid, lut[tid]);
    const int lane = tid & 63, wid = tid >> 6;   // 8 waves
    const int fr = lane & 15, fo = lane >> 4;
    const int n0 = wid * 16;

    s16x8 bh[16], bl[16];
#pragma unroll
    for (int ks = 0; ks < 16; ++ks) {
        int off = (n0 + fr) * 512 + ks * 32 + fo * 8;
        bh[ks] = *(const s16x8*)(whi + off);
        bl[ks] = *(const s16x8*)(wlo + off);
    }
    __syncthreads();

    const int m0 = blockIdx.x * 160;
    for (int mt = 0; mt < 10; ++mt) {
        int mrow = m0 + mt * 16 + fr;
        u32x4 w0 = *(const u32x4*)&spk[mrow * 16];
        u32x4 w1 = *(const u32x4*)&spk[mrow * 16 + 4];
        u32x4 w2 = *(const u32x4*)&spk[mrow * 16 + 8];
        u32x4 w3 = *(const u32x4*)&spk[mrow * 16 + 12];
        f32x4 acc = (f32x4)0.f;
#pragma unroll
        for (int ks = 0; ks < 16; ++ks) {
            uint32_t word = (ks < 4) ? w0[ks & 3] : (ks < 8) ? w1[ks & 3]
                          : (ks < 12) ? w2[ks & 3] : w3[ks & 3];
            uint32_t by = (word >> (fo * 8)) & 0xFFu;
            union { u32x4 u; s16x8 v; } cv;
            cv.u = *(const u32x4*)lut[by];
            s16x8 af = cv.v;
            acc = __builtin_amdgcn_mfma_f32_16x16x32_bf16(af, bh[ks], acc, 0, 0, 0);
            acc = __builtin_amdgcn_mfma_f32_16x16x32_bf16(af, bl[ks], acc, 0, 0, 0);
        }
        int row0 = m0 + mt * 16 + fo * 4;
        int col = n0 + fr;
#pragma unroll
        for (int r = 0; r < 4; ++r)
            I[(size_t)(row0 + r) * 128 + col] = acc[r];
    }
}

// K_C: recurrent LIF. 128 thr/block (2 waves), 1 channel/thread, 1 batch row/block.
// Weights register-resident (128 VGPR). Masks -> SGPR via LDS + readfirstlane.
// rec chain: ch 0..127 ascending, single accumulator — bitwise identical to R5.
__global__ __launch_bounds__(128, 2) void k_recur(const float* __restrict__ I,
                                                  const float* __restrict__ w_rec,
                                                  unsigned long long* __restrict__ zbits) {
    __shared__ unsigned long long zx[2][2];   // [t-parity][wave]
    const int tid = threadIdx.x;
    const int h = tid;                        // channel 0..127
    const int wid = tid >> 6;
    const int lane = tid & 63;
    const int b = blockIdx.x;

    float wreg[128];
#pragma unroll
    for (int j = 0; j < 32; ++j) {
        float4 w4 = *(const float4*)&w_rec[h * 128 + j * 4];
        wreg[j * 4 + 0] = w4.x; wreg[j * 4 + 1] = w4.y;
        wreg[j * 4 + 2] = w4.z; wreg[j * 4 + 3] = w4.w;
    }

    float v = 0.f, ci = 0.f;
    float Ih = I[(size_t)b * 128 + h];
    uint32_t ma0 = 0, ma1 = 0, mb0 = 0, mb1 = 0;    // z_{t-1} masks (uniform SGPRs)
    unsigned long long* zout = zbits + (size_t)b * 2;

    for (int t = 0; t < 40; ++t) {
        int tn = (t < 39) ? t + 1 : 39;
        float nI = I[(size_t)(tn * 1024 + b) * 128 + h];

        // recurrent drive from z_{t-1}: ascending single-acc fmaf chain (R5 order)
        float rec = 0.f;
#pragma unroll
        for (int j = 0; j < 32; ++j) {
            float zf = ((ma0 >> j) & 1u) ? 1.0f : 0.0f;
            rec = fmaf(zf, wreg[j], rec);
        }
#pragma unroll
        for (int j = 0; j < 32; ++j) {
            float zf = ((ma1 >> j) & 1u) ? 1.0f : 0.0f;
            rec = fmaf(zf, wreg[32 + j], rec);
        }
#pragma unroll
        for (int j = 0; j < 32; ++j) {
            float zf = ((mb0 >> j) & 1u) ? 1.0f : 0.0f;
            rec = fmaf(zf, wreg[64 + j], rec);
        }
#pragma unroll
        for (int j = 0; j < 32; ++j) {
            float zf = ((mb1 >> j) & 1u) ? 1.0f : 0.0f;
            rec = fmaf(zf, wreg[96 + j], rec);
        }

        // LIF update — verbatim R5 expressions
        float vd = v + 0.1f * (ci - v);
        float id = ci - 0.2f * ci;
        bool z = (vd - 1.0f) > 0.f;
        unsigned long long m = __ballot(z);
        v = z ? 0.f : vd;
        if (lane == 0) {
            zout[(size_t)t * 2048 + wid] = m;
            zx[t & 1][wid] = m;
        }
        ci = id + Ih + rec;            // (i_dec + I_t) + rec, R5 association
        Ih = nI;
        __syncthreads();
        unsigned long long M0 = zx[t & 1][0];
        unsigned long long M1 = zx[t & 1][1];
        ma0 = __builtin_amdgcn_readfirstlane((uint32_t)M0);
        ma1 = __builtin_amdgcn_readfirstlane((uint32_t)(M0 >> 32));
        mb0 = __builtin_amdgcn_readfirstlane((uint32_t)M1);
        mb1 = __builtin_amdgcn_readfirstlane((uint32_t)(M1 >> 32));
    }
}

// K_D: fused readout GEMM + LI scan + max + softmax.
// 64 blocks x 1 wave; wave owns 16 batch rows across all 40 steps.
// LI state lives in MFMA accumulator lane layout: lane(fo,fr) reg r ->
// (batch row = b0 + fo*4 + r, a-channel = ni*16 + fr).
__global__ __launch_bounds__(64) void k_readout(const uint32_t* __restrict__ zb,
                                                const __hip_bfloat16* __restrict__ wahi,
                                                const __hip_bfloat16* __restrict__ walo,
                                                float* __restrict__ out) {
    __shared__ uint32_t lut[256][4];
    const int lane = threadIdx.x;
    for (int i0 = lane; i0 < 256; i0 += 64) lut_entry(i0, lut[i0]);
    const int fr = lane & 15, fo = lane >> 4;
    const int b0 = blockIdx.x * 16;

    s16x8 bf[2][4][2];
#pragma unroll
    for (int ni = 0; ni < 2; ++ni)
#pragma unroll
        for (int ks = 0; ks < 4; ++ks) {
            int off = (ni * 16 + fr) * 128 + ks * 32 + fo * 8;
            bf[ni][ks][0] = *(const s16x8*)(wahi + off);
            bf[ni][ks][1] = *(const s16x8*)(walo + off);
        }
    __syncthreads();

    f32x4 va[2], ia[2], ma_[2];
#pragma unroll
    for (int ni = 0; ni < 2; ++ni) {
        va[ni] = (f32x4)0.f; ia[ni] = (f32x4)0.f; ma_[ni] = (f32x4)(-1e30f);
    }

    for (int t = 0; t < 40; ++t) {
        int m = t * 1024 + b0 + fr;
        u32x4 zw = *(const u32x4*)&zb[(size_t)m * 4];
        f32x4 acc[2];
        acc[0] = (f32x4)0.f; acc[1] = (f32x4)0.f;
#pragma unroll
        for (int ks = 0; ks < 4; ++ks) {
            uint32_t by = (zw[ks] >> (fo * 8)) & 0xFFu;
            union { u32x4 u; s16x8 v; } cv;
            cv.u = *(const u32x4*)lut[by];
            s16x8 af = cv.v;
            acc[0] = __builtin_amdgcn_mfma_f32_16x16x32_bf16(af, bf[0][ks][0], acc[0], 0, 0, 0);
            acc[0] = __builtin_amdgcn_mfma_f32_16x16x32_bf16(af, bf[0][ks][1], acc[0], 0, 0, 0);
            acc[1] = __builtin_amdgcn_mfma_f32_16x16x32_bf16(af, bf[1][ks][0], acc[1], 0, 0, 0);
            acc[1] = __builtin_amdgcn_mfma_f32_16x16x32_bf16(af, bf[1][ks][1], acc[1], 0, 0, 0);
        }
        // LI update (k_scan expressions, elementwise)
#pragma unroll
        for (int ni = 0; ni < 2; ++ni) {
            f32x4 nva = va[ni] + 0.1f * (ia[ni] - va[ni]);
            ia[ni] = ia[ni] - 0.2f * ia[ni] + acc[ni];
            va[ni] = nva;
#pragma unroll
            for (int r = 0; r < 4; ++r)
                ma_[ni][r] = fmaxf(ma_[ni][r], nva[r]);
        }
    }

    // per-row softmax over a=0..17 (16-lane group reduce), critic = a=18
#pragma unroll
    for (int r = 0; r < 4; ++r) {
        int b = b0 + fo * 4 + r;
        float x0 = ma_[0][r];
        float x1 = (fr < 2) ? ma_[1][r] : -1e30f;
        float mx = fmaxf(x0, x1);
#pragma unroll
        for (int d = 1; d < 16; d <<= 1) mx = fmaxf(mx, __shfl_xor(mx, d));
        float e0 = expf(x0 - mx);
        float e1 = (fr < 2) ? expf(ma_[1][r] - mx) : 0.f;
        float s = e0 + e1;
#pragma unroll
        for (int d = 1; d < 16; d <<= 1) s += __shfl_xor(s, d);
        out[b * 18 + fr] = e0 / s;
        if (fr < 2) out[b * 18 + 16 + fr] = e1 / s;
        if (fr == 2) out[18432 + b] = ma_[1][r];
    }
}

extern "C" void kernel_launch(void* const* d_in, const int* in_sizes, int n_in,
                              void* d_out, int out_size, void* d_ws, size_t ws_size,
                              hipStream_t stream) {
    const float* x        = (const float*)d_in[0];
    const float* w_in     = (const float*)d_in[1];
    const float* w_rec    = (const float*)d_in[2];
    const float* w_actor  = (const float*)d_in[3];
    const float* w_critic = (const float*)d_in[4];
    float* out = (float*)d_out;
    char* ws = (char*)d_ws;
    uint32_t*           spk  = (uint32_t*)ws;
    __hip_bfloat16*     whi  = (__hip_bfloat16*)(ws + OFF_WHI);
    __hip_bfloat16*     wlo  = (__hip_bfloat16*)(ws + OFF_WLO);
    __hip_bfloat16*     wahi = (__hip_bfloat16*)(ws + OFF_WAHI);
    __hip_bfloat16*     walo = (__hip_bfloat16*)(ws + OFF_WALO);
    float*              I    = (float*)(ws + OFF_I);
    unsigned long long* zb   = (unsigned long long*)(ws + OFF_ZB);

    hipLaunchKernelGGL(k_prep_enc, dim3(2304), dim3(256), 0, stream,
                       x, w_in, w_actor, w_critic, spk, whi, wlo, wahi, walo);
    hipLaunchKernelGGL(k_ingemm,   dim3(256),  dim3(512), 0, stream, spk, whi, wlo, I);
    hipLaunchKernelGGL(k_recur,    dim3(1024), dim3(128), 0, stream, I, w_rec, zb);
    hipLaunchKernelGGL(k_readout,  dim3(64),   dim3(64),  0, stream,
                       (const uint32_t*)zb, wahi, walo, out);
}